// Round 6
// baseline (281.944 us; speedup 1.0000x reference)
//
#include <hip/hip_runtime.h>
#include <hip/hip_bf16.h>

constexpr int T   = 16384;  // tokens
constexpr int HD  = 4096;   // hidden dim
constexpr int E   = 64;     // experts
constexpr int BK  = 32;     // k per chunk
constexpr int KS  = 4;      // K-split across the 4 waves of a block
constexpr int NCW = HD / (KS * BK);  // 32 chunks per wave

using short8 = __attribute__((ext_vector_type(8))) short;
using f32x4  = __attribute__((ext_vector_type(4))) float;

__device__ __forceinline__ unsigned short f2bf(float x) {
  union { float f; unsigned u; } v; v.f = x;
  return (unsigned short)((v.u + 0x7FFFu + ((v.u >> 16) & 1u)) >> 16);
}
__device__ __forceinline__ float bf2f(unsigned short h) {
  union { float f; unsigned u; } v; v.u = ((unsigned)h) << 16;
  return v.f;
}

// ---------------------------------------------------------------------------
// Kernel 0: pack W (fp32 [64][4096]) into bf16 hi/lo image, plain layout:
// img[chunk 128][expert 64][slot 8] x 16B; slot 0..3 = hi k-groups (8 bf16 of
// k [8s..8s+8)), 4..7 = lo of group s-4.
// ---------------------------------------------------------------------------
__global__ __launch_bounds__(256) void wprep(const float* __restrict__ W,
                                             short* __restrict__ img) {
  const int tid = blockIdx.x * 256 + threadIdx.x;   // 0..65535
  const int c   = tid >> 9;
  const int rem = tid & 511;
  const int e   = rem >> 3;
  const int sp  = rem & 7;
  const int part = sp >> 2;   // 0 = hi, 1 = lo
  const int sl   = sp & 3;    // k-group
  const float* src = W + (size_t)e * HD + c * BK + sl * 8;
  short8 v;
#pragma unroll
  for (int j = 0; j < 8; ++j) {
    float x = src[j];
    unsigned short h = f2bf(x);
    v[j] = part ? (short)f2bf(x - bf2f(h)) : (short)h;
  }
  *(short8*)(img + (size_t)tid * 8) = v;
}

// ---------------------------------------------------------------------------
// Kernel 1: fused router. 1024 blocks x 256 threads (4 waves) = 4 blocks/CU,
// 16 waves/CU. All 4 waves of a block share the SAME 16 token rows; wave w
// computes the partial logits for k in [1024w, 1024w+1024) — LDS-free,
// barrier-free K-loop (global->VGPR, split-bf16 MFMA, 3 terms). Epilogue:
// LDS reduction across waves + logits write + fused softmax top-2 + renorm.
// ---------------------------------------------------------------------------
__global__ __launch_bounds__(256, 4) void router_fused(
    const float* __restrict__ H, const short* __restrict__ img,
    float* __restrict__ logits, float* __restrict__ topw, float* __restrict__ topi) {
  __shared__ float part[KS * 16 * E];   // 16 KB: per-wave 16x64 partials

  const int tid  = threadIdx.x;
  const int w    = tid >> 6;    // wave = K-quarter
  const int lane = tid & 63;
  const int q    = lane >> 4;   // k-group / C row-group
  const int r    = lane & 15;   // A row / B expert sub-index
  const int row0 = blockIdx.x * 16;

  const float* pA = H + (size_t)(row0 + r) * HD + w * 1024 + q * 8;
  const short* pB = img + r * 64 + q * 8 + (size_t)(w * NCW) * 4096;

  f32x4  Ab[4][2];            // depth-4 A prefetch (raw fp32)
  short8 Bh[2][4], Bl[2][4];  // depth-2 B prefetch
  f32x4  acc[4];
#pragma unroll
  for (int ct = 0; ct < 4; ++ct)
#pragma unroll
    for (int i = 0; i < 4; ++i) acc[ct][i] = 0.f;

  // HW packed f32->bf16 split: hi = rne(x,y), lo = rne(residual)
  auto cvtpk = [&](float x, float y, unsigned& hw, unsigned& lw) {
    union { __hip_bfloat162 b; unsigned u; } Hh, Ll;
    Hh.b = __float22bfloat162_rn(float2{x, y});
    float2 hf = __bfloat1622float2(Hh.b);
    Ll.b = __float22bfloat162_rn(float2{x - hf.x, y - hf.y});
    hw = Hh.u; lw = Ll.u;
  };

  // prologue: A(0..3), B(0..1)
#pragma unroll
  for (int i = 0; i < 4; ++i) {
    Ab[i][0] = *(const f32x4*)(pA + i * BK);
    Ab[i][1] = *(const f32x4*)(pA + i * BK + 4);
  }
#pragma unroll
  for (int i = 0; i < 2; ++i)
#pragma unroll
    for (int ct = 0; ct < 4; ++ct) {
      Bh[i][ct] = *(const short8*)(pB + ct * 1024 + (size_t)i * 4096);
      Bl[i][ct] = *(const short8*)(pB + ct * 1024 + (size_t)i * 4096 + 32);
    }

#define GEMM_BODY(U, TT, PREA, PREB)                                            \
  {                                                                             \
    f32x4 a0 = Ab[U][0], a1 = Ab[U][1];                                         \
    short8 bh0 = Bh[(U)&1][0], bh1 = Bh[(U)&1][1],                              \
           bh2 = Bh[(U)&1][2], bh3 = Bh[(U)&1][3];                              \
    short8 bl0 = Bl[(U)&1][0], bl1 = Bl[(U)&1][1],                              \
           bl2 = Bl[(U)&1][2], bl3 = Bl[(U)&1][3];                              \
    if (PREA) {                                                                 \
      Ab[U][0] = *(const f32x4*)(pA + ((TT) + 4) * BK);                         \
      Ab[U][1] = *(const f32x4*)(pA + ((TT) + 4) * BK + 4);                     \
    }                                                                           \
    if (PREB) {                                                                 \
      _Pragma("unroll")                                                         \
      for (int ct = 0; ct < 4; ++ct) {                                          \
        Bh[(U)&1][ct] = *(const short8*)(pB + ct * 1024 + (size_t)((TT) + 2) * 4096);      \
        Bl[(U)&1][ct] = *(const short8*)(pB + ct * 1024 + (size_t)((TT) + 2) * 4096 + 32); \
      }                                                                         \
    }                                                                           \
    union { short8 s; unsigned u[4]; } AH, AL;                                  \
    cvtpk(a0[0], a0[1], AH.u[0], AL.u[0]);                                      \
    cvtpk(a0[2], a0[3], AH.u[1], AL.u[1]);                                      \
    cvtpk(a1[0], a1[1], AH.u[2], AL.u[2]);                                      \
    cvtpk(a1[2], a1[3], AH.u[3], AL.u[3]);                                      \
    acc[0] = __builtin_amdgcn_mfma_f32_16x16x32_bf16(AH.s, bh0, acc[0], 0, 0, 0);\
    acc[0] = __builtin_amdgcn_mfma_f32_16x16x32_bf16(AL.s, bh0, acc[0], 0, 0, 0);\
    acc[0] = __builtin_amdgcn_mfma_f32_16x16x32_bf16(AH.s, bl0, acc[0], 0, 0, 0);\
    acc[1] = __builtin_amdgcn_mfma_f32_16x16x32_bf16(AH.s, bh1, acc[1], 0, 0, 0);\
    acc[1] = __builtin_amdgcn_mfma_f32_16x16x32_bf16(AL.s, bh1, acc[1], 0, 0, 0);\
    acc[1] = __builtin_amdgcn_mfma_f32_16x16x32_bf16(AH.s, bl1, acc[1], 0, 0, 0);\
    acc[2] = __builtin_amdgcn_mfma_f32_16x16x32_bf16(AH.s, bh2, acc[2], 0, 0, 0);\
    acc[2] = __builtin_amdgcn_mfma_f32_16x16x32_bf16(AL.s, bh2, acc[2], 0, 0, 0);\
    acc[2] = __builtin_amdgcn_mfma_f32_16x16x32_bf16(AH.s, bl2, acc[2], 0, 0, 0);\
    acc[3] = __builtin_amdgcn_mfma_f32_16x16x32_bf16(AH.s, bh3, acc[3], 0, 0, 0);\
    acc[3] = __builtin_amdgcn_mfma_f32_16x16x32_bf16(AL.s, bh3, acc[3], 0, 0, 0);\
    acc[3] = __builtin_amdgcn_mfma_f32_16x16x32_bf16(AH.s, bl3, acc[3], 0, 0, 0);\
  }

  for (int t0 = 0; t0 <= NCW - 8; t0 += 4) {   // t0 = 0..24
    GEMM_BODY(0, t0 + 0, true, true)
    GEMM_BODY(1, t0 + 1, true, true)
    GEMM_BODY(2, t0 + 2, true, true)
    GEMM_BODY(3, t0 + 3, true, true)
  }
  // tail: t = 28..31 (A resident; B(30),B(31) still to prefetch)
  GEMM_BODY(0, NCW - 4, false, true)
  GEMM_BODY(1, NCW - 3, false, true)
  GEMM_BODY(2, NCW - 2, false, false)
  GEMM_BODY(3, NCW - 1, false, false)
#undef GEMM_BODY

  // --- store partials: D layout col = lane&15(=r), row = 4q+rr ---
#pragma unroll
  for (int ct = 0; ct < 4; ++ct)
#pragma unroll
    for (int rr = 0; rr < 4; ++rr)
      part[w * 1024 + (4 * q + rr) * E + 16 * ct + r] = acc[ct][rr];
  __syncthreads();

  // --- reduce across the 4 K-quarters: thread tid owns 4 consecutive floats ---
  f32x4 s = *(const f32x4*)(part + tid * 4);
#pragma unroll
  for (int ww = 1; ww < KS; ++ww) s += *(const f32x4*)(part + ww * 1024 + tid * 4);

  // logits write (row-major [16][64] tile, coalesced 16B stores)
  *(f32x4*)(logits + (size_t)row0 * E + tid * 4) = s;
  *(f32x4*)(part + tid * 4) = s;
  __syncthreads();

  // --- fused top-2 + renorm: threads 0..15, one row each ---
  if (tid < 16) {
    const float* rowp = part + tid * E;
    float bv = rowp[0]; int bi = 0;
#pragma unroll 8
    for (int e = 1; e < E; ++e) {
      float v = rowp[e];
      if (v > bv) { bv = v; bi = e; }
    }
    float sv = -3.4e38f; int si = 0;
#pragma unroll 8
    for (int e = 0; e < E; ++e) {
      float v = rowp[e];
      if (e != bi && v > sv) { sv = v; si = e; }
    }
    // w1 = p1/(p1+p2) = 1/(1+e^{x2-x1}); softmax denominator cancels
    const float w1 = 1.0f / (1.0f + __expf(sv - bv));
    const int R = row0 + tid;
    topw[(size_t)R * 2 + 0] = w1;
    topw[(size_t)R * 2 + 1] = 1.0f - w1;
    topi[(size_t)R * 2 + 0] = (float)bi;
    topi[(size_t)R * 2 + 1] = (float)si;
  }
}

extern "C" void kernel_launch(void* const* d_in, const int* in_sizes, int n_in,
                              void* d_out, int out_size, void* d_ws, size_t ws_size,
                              hipStream_t stream) {
  const float* H = (const float*)d_in[0];  // [16384, 4096] fp32
  const float* W = (const float*)d_in[1];  // [64, 4096] fp32

  float* out    = (float*)d_out;
  float* topw   = out;                       // [16384, 2]
  float* logits = out + (size_t)T * 2;       // [16384, 64]
  float* topi   = logits + (size_t)T * E;    // [16384, 2] (indices as float)

  short* wimg = (short*)d_ws;                // 1 MiB packed W image

  wprep<<<256, 256, 0, stream>>>(W, wimg);
  router_fused<<<T / 16, 256, 0, stream>>>(H, wimg, logits, topw, topi);
}

// Round 7
// 97.283 us; speedup vs baseline: 2.8982x; 2.8982x over previous
//
#include <hip/hip_runtime.h>
#include <hip/hip_bf16.h>

constexpr int T   = 16384;  // tokens
constexpr int HD  = 4096;   // hidden dim
constexpr int E   = 64;     // experts
constexpr int BK  = 64;     // k per chunk
constexpr int NCH = HD / BK;  // 64 chunks
constexpr int BM  = 32;     // rows per block

using short8 = __attribute__((ext_vector_type(8))) short;
using f32x4  = __attribute__((ext_vector_type(4))) float;

#define AS1 __attribute__((address_space(1)))
#define AS3 __attribute__((address_space(3)))

__device__ __forceinline__ unsigned short f2bf(float x) {
  union { float f; unsigned u; } v; v.f = x;
  return (unsigned short)((v.u + 0x7FFFu + ((v.u >> 16) & 1u)) >> 16);
}
__device__ __forceinline__ float bf2f(unsigned short h) {
  union { float f; unsigned u; } v; v.u = ((unsigned)h) << 16;
  return v.f;
}

__device__ __forceinline__ void gload16(const void* g, void* l) {
  __builtin_amdgcn_global_load_lds((const AS1 void*)g, (AS3 void*)l, 16, 0, 0);
}

// ---------------------------------------------------------------------------
// Kernel 0: pack W (fp32 [64][4096]) into a bf16 hi/lo image laid out for
// contiguous per-wave global loads:
//   img[chunk 64][kk 2][part 2][expert 64][q 4] x 8 shorts (16B)
// part 0 = hi bf16 of k-group g = 4*kk+q (8 k's), part 1 = lo residual.
// A wave (fixed chunk,kk,part,ct) reads experts 16ct..16ct+15 x q 0..3 =
// contiguous 1 KB.
// ---------------------------------------------------------------------------
__global__ __launch_bounds__(256) void wprep(const float* __restrict__ W,
                                             short* __restrict__ img) {
  const int tid  = blockIdx.x * 256 + threadIdx.x;  // 0..65535
  const int c    = tid >> 10;         // chunk
  const int kk   = (tid >> 9) & 1;
  const int part = (tid >> 8) & 1;
  const int e    = (tid >> 2) & 63;
  const int q    = tid & 3;
  const int g    = 4 * kk + q;        // k-group within chunk
  const float* src = W + (size_t)e * HD + c * BK + g * 8;
  short8 v;
#pragma unroll
  for (int j = 0; j < 8; ++j) {
    float x = src[j];
    unsigned short h = f2bf(x);
    v[j] = part ? (short)f2bf(x - bf2f(h)) : (short)h;
  }
  *(short8*)(img + (size_t)tid * 8) = v;
}

// ---------------------------------------------------------------------------
// Kernel 1: logits = H x W^T (split-bf16 MFMA, 3 terms) + fused top-2.
// 512 blocks x 512 threads (8 waves) = 2 blocks/CU, 16 waves/CU.
// Wave w: row-tile rt=w>>2 (16 rows), col-tile ct=w&3 (16 experts).
// A: DMA->LDS, triple-buffered, staged depth-2 (round-4 proven pattern).
// B: global->VGPR, depth-1 register prefetch, folded into the same counted
// vmcnt stream: steady-state vmcnt(5) = {A(t+2) dma, B(t+1) x4} in flight.
// LDS traffic is A-only (~900cy/CU/chunk << 1560cy HBM budget).
// ---------------------------------------------------------------------------
__global__ __launch_bounds__(512, 4) void router_gemm(
    const float* __restrict__ H, const short* img,
    float* __restrict__ logits, float* topw, float* topi) {
  // A: 3 x 8 KB @ 0; cand: 2 KB @ 24 KB
  __shared__ __align__(16) char lds[26624];
  char* const ldsA = lds;
  float* const cand = (float*)(lds + 24576);  // [32 rows][4 ct][v1,i1,v2,i2]

  const int tid  = threadIdx.x;
  const int w    = tid >> 6;
  const int lane = tid & 63;
  const int q    = lane >> 4;   // 0..3
  const int r    = lane & 15;   // 0..15
  const int rt   = w >> 2;      // row-tile 0..1
  const int ct   = w & 3;       // col-tile 0..3
  const int row0 = blockIdx.x * BM;

  f32x4 acc = {0.f, 0.f, 0.f, 0.f};

  // --- A staging: 1 DMA inst per wave per chunk (wave-uniform LDS base) ---
  auto stageA = [&](int c, int buf) {
    const int R  = tid >> 4;
    const int sp = tid & 15;
    const int s  = (sp & 8) | ((sp & 7) ^ (R & 7));
    const char* src = (const char*)(H + (size_t)(row0 + R) * HD + c * BK) + s * 16;
    gload16(src, ldsA + buf * 8192 + w * 1024);  // HW adds lane*16
  };

  // --- B register prefetch: 4 x 1KB contiguous loads per wave per chunk ---
  // lane (q,r) of wave ct reads expert e=16ct+r, k-group 4kk+q, part hi/lo.
  const short* pBe = img + ((size_t)(16 * ct + r) * 4 + q) * 8;
  short8 Bh[2][2], Bl[2][2];   // [parity][kk] — all indices compile-time
  auto loadB = [&](int t, int s) {
#pragma unroll
    for (int kk = 0; kk < 2; ++kk) {
      Bh[s][kk] = *(const short8*)(pBe + (size_t)t * 8192 + kk * 4096);
      Bl[s][kk] = *(const short8*)(pBe + (size_t)t * 8192 + kk * 4096 + 2048);
    }
  };

  const int Arow = 16 * rt + r;
  const int ra   = r & 7;

  // HW packed f32->bf16 split: hi = rne(x,y), lo = rne(residual)
  auto cvtpk = [&](float x, float y, unsigned& hw, unsigned& lw) {
    union { __hip_bfloat162 b; unsigned u; } Hh, Ll;
    Hh.b = __float22bfloat162_rn(float2{x, y});
    float2 hf = __bfloat1622float2(Hh.b);
    Ll.b = __float22bfloat162_rn(float2{x - hf.x, y - hf.y});
    hw = Hh.u; lw = Ll.u;
  };

  auto compute = [&](int abuf, int s) {
    const char* Ab = ldsA + abuf * 8192 + Arow * 256;
#pragma unroll
    for (int kk = 0; kk < 2; ++kk) {
      const int s0  = 8 * kk + 2 * q;
      const int sp0 = (s0 & 8) | ((s0 & 7) ^ ra);
      const int s1  = s0 + 1;
      const int sp1 = (s1 & 8) | ((s1 & 7) ^ ra);
      f32x4 a0 = *(const f32x4*)(Ab + sp0 * 16);
      f32x4 a1 = *(const f32x4*)(Ab + sp1 * 16);
      union { short8 v; unsigned u[4]; } AH, AL;
      cvtpk(a0[0], a0[1], AH.u[0], AL.u[0]);
      cvtpk(a0[2], a0[3], AH.u[1], AL.u[1]);
      cvtpk(a1[0], a1[1], AH.u[2], AL.u[2]);
      cvtpk(a1[2], a1[3], AH.u[3], AL.u[3]);
      acc = __builtin_amdgcn_mfma_f32_16x16x32_bf16(AH.v, Bh[s][kk], acc, 0, 0, 0);
      acc = __builtin_amdgcn_mfma_f32_16x16x32_bf16(AL.v, Bh[s][kk], acc, 0, 0, 0);
      acc = __builtin_amdgcn_mfma_f32_16x16x32_bf16(AH.v, Bl[s][kk], acc, 0, 0, 0);
    }
  };

  // --- prologue: A(0), A(1), B(0) -> 6 vmem outstanding per wave ---
  stageA(0, 0);
  stageA(1, 1);
  loadB(0, 0);

  int ab = 0;  // LDS buffer holding chunk t (t mod 3)
  // steady state entering each body: 5 outstanding = {A(t+1), B(t) x4}
  for (int t = 0; t < NCH - 2; t += 2) {
    {  // even body: compute(t) with B parity 0
      int nb = ab + 2; if (nb >= 3) nb -= 3;
      stageA(t + 2, nb);
      loadB(t + 1, 1);
      asm volatile("s_waitcnt vmcnt(5)\n\ts_barrier" ::: "memory");
      compute(ab, 0);
      ab = (ab == 2) ? 0 : ab + 1;
    }
    {  // odd body: compute(t+1) with B parity 1
      int nb = ab + 2; if (nb >= 3) nb -= 3;
      stageA(t + 3, nb);
      loadB(t + 2, 0);
      asm volatile("s_waitcnt vmcnt(5)\n\ts_barrier" ::: "memory");
      compute(ab, 1);
      ab = (ab == 2) ? 0 : ab + 1;
    }
  }
  // t = NCH-2 (even): B(NCH-1) into parity 1; A(NCH-1) already staged
  loadB(NCH - 1, 1);
  asm volatile("s_waitcnt vmcnt(5)\n\ts_barrier" ::: "memory");
  compute(ab, 0);
  ab = (ab == 2) ? 0 : ab + 1;
  // t = NCH-1
  asm volatile("s_waitcnt vmcnt(0)\n\ts_barrier" ::: "memory");
  compute(ab, 1);

  // --- epilogue: logits write (D layout: col = lane&15, row = 4q+rr) ---
  const int orow0 = row0 + 16 * rt + 4 * q;
#pragma unroll
  for (int rr = 0; rr < 4; ++rr)
    logits[(size_t)(orow0 + rr) * E + 16 * ct + r] = acc[rr];

  // per-wave top-2 over this wave's 16 experts, for each of its 4 rows
#pragma unroll
  for (int rr = 0; rr < 4; ++rr) {
    const int myi = 16 * ct + r;
    float v1 = acc[rr]; int i1 = myi;
#pragma unroll
    for (int off = 1; off < 16; off <<= 1) {
      float ov = __shfl_xor(v1, off); int oi = __shfl_xor(i1, off);
      if (ov > v1 || (ov == v1 && oi < i1)) { v1 = ov; i1 = oi; }
    }
    float v2 = (myi == i1) ? -3.4e38f : acc[rr]; int i2 = myi;
#pragma unroll
    for (int off = 1; off < 16; off <<= 1) {
      float ov = __shfl_xor(v2, off); int oi = __shfl_xor(i2, off);
      if (ov > v2 || (ov == v2 && oi < i2)) { v2 = ov; i2 = oi; }
    }
    if (r == 0) {
      float* cd = cand + ((size_t)(16 * rt + 4 * q + rr) * 4 + ct) * 4;
      cd[0] = v1; cd[1] = (float)i1; cd[2] = v2; cd[3] = (float)i2;
    }
  }
  __syncthreads();

  // merge 4 col-tile candidate pairs per row; renormalized top-2 weights
  if (tid < BM) {
    const float* cd = cand + (size_t)tid * 16;   // 8 (v,i) pairs
    float bv = -3.4e38f; int bi = 1 << 30;
#pragma unroll
    for (int j = 0; j < 8; ++j) {
      float v = cd[2 * j]; int i = (int)cd[2 * j + 1];
      if (v > bv || (v == bv && i < bi)) { bv = v; bi = i; }
    }
    float sv = -3.4e38f; int si = 1 << 30;
#pragma unroll
    for (int j = 0; j < 8; ++j) {
      float v = cd[2 * j]; int i = (int)cd[2 * j + 1];
      if (i != bi && (v > sv || (v == sv && i < si))) { sv = v; si = i; }
    }
    // w1 = p1/(p1+p2) = 1/(1+e^{x2-x1}); softmax denominator cancels
    const float w1 = 1.0f / (1.0f + __expf(sv - bv));
    const int R = row0 + tid;
    topw[(size_t)R * 2 + 0] = w1;
    topw[(size_t)R * 2 + 1] = 1.0f - w1;
    topi[(size_t)R * 2 + 0] = (float)bi;
    topi[(size_t)R * 2 + 1] = (float)si;
  }
}

extern "C" void kernel_launch(void* const* d_in, const int* in_sizes, int n_in,
                              void* d_out, int out_size, void* d_ws, size_t ws_size,
                              hipStream_t stream) {
  const float* H = (const float*)d_in[0];  // [16384, 4096] fp32
  const float* W = (const float*)d_in[1];  // [64, 4096] fp32

  float* out    = (float*)d_out;
  float* topw   = out;                       // [16384, 2]
  float* logits = out + (size_t)T * 2;       // [16384, 64]
  float* topi   = logits + (size_t)T * E;    // [16384, 2] (indices as float)

  short* wimg = (short*)d_ws;                // 1 MiB packed W image

  wprep<<<256, 256, 0, stream>>>(W, wimg);
  router_gemm<<<T / BM, 512, 0, stream>>>(H, wimg, logits, topw, topi);
}